// Round 1
// baseline (426.821 us; speedup 1.0000x reference)
//
#include <hip/hip_runtime.h>
#include <hip/hip_bf16.h>

// Problem constants (from reference): B=256, T=256, C=1024, L=64, S=2L+1=129
// blank = C-1 = 1023. EPS = 1e-7, C*EPS = 1.024e-4.
//
// Math: logp[b,t,c] = log(y+EPS) - log(rowsum + C*EPS)   (log_softmax collapses)
// Only 65 classes per (b,t) are ever used: the 64 labels + blank.
// All logs kept in BASE 2 (native v_exp_f32/v_log_f32 are 2^x / log2 x);
// final loglik multiplied by ln2.

#define NEGF (-1e30f)

__device__ __forceinline__ float lse2(float a, float b) {
    float m = fmaxf(a, b);
    return m + log2f(exp2f(a - m) + exp2f(b - m));
}
__device__ __forceinline__ float lse3(float a, float b, float c) {
    float m = fmaxf(fmaxf(a, b), c);
    return m + log2f(exp2f(a - m) + exp2f(b - m) + exp2f(c - m));
}

// One wave per (b,t) row: rowsum over C=1024 via 4x float4 + shfl reduction,
// then gather the 64 label probs (+ blank) from the L1-hot row.
// lpl layout: [row][64] (row = b*256+t), lpb: [row].
__global__ void __launch_bounds__(256) emit_kernel(
    const float* __restrict__ y, const int* __restrict__ lab,
    float* __restrict__ lpl, float* __restrict__ lpb) {
    const int wave = threadIdx.x >> 6;
    const int lane = threadIdx.x & 63;
    const int row  = (blockIdx.x << 2) + wave;   // b*T + t
    const int b    = row >> 8;                   // T = 256
    const float* __restrict__ yr = y + ((size_t)row << 10);
    const float4* __restrict__ yr4 = (const float4*)yr;

    float4 v0 = yr4[lane];
    float4 v1 = yr4[lane + 64];
    float4 v2 = yr4[lane + 128];
    float4 v3 = yr4[lane + 192];
    float s = (v0.x + v0.y + v0.z + v0.w) + (v1.x + v1.y + v1.z + v1.w)
            + (v2.x + v2.y + v2.z + v2.w) + (v3.x + v3.y + v3.z + v3.w);
    #pragma unroll
    for (int off = 32; off; off >>= 1) s += __shfl_xor(s, off);

    const float norm = log2f(s + 1.024e-4f);   // log2(rowsum + C*EPS)

    const int c = lab[(b << 6) + lane];        // label gather (row is L1-hot)
    const float yv = yr[c];
    lpl[((size_t)row << 6) + lane] = log2f(yv + 1e-7f) - norm;
    if (lane == 0)
        lpb[row] = log2f(yr[1023] + 1e-7f) - norm;  // blank = C-1
}

// One wave per batch element. Lane j holds alpha[2j] (blank pos, a0) and
// alpha[2j+1] (label j, a1); alpha[128] (a2) replicated across lanes.
// Recursion (skip_ok is false at all even positions since ext==blank there;
// true at odd position 2j+1 iff j>=1 && lab[j]!=lab[j-1]):
//   a0' = LSE(a0, alpha[2j-1]) + lp_blank
//   a1' = LSE(a1, a0, skip ? alpha[2j-1] : -inf) + lp_label_j
//   a2' = LSE(a2, alpha[127]) + lp_blank
__global__ void __launch_bounds__(64) ctc_alpha_kernel(
    const int* __restrict__ lab,
    const float* __restrict__ lpl, const float* __restrict__ lpb,
    float* __restrict__ out) {
    const int b    = blockIdx.x;
    const int lane = threadIdx.x;                 // 0..63

    const int myLab   = lab[(b << 6) + lane];
    const int prevLab = __shfl_up(myLab, 1);
    const bool skip   = (lane >= 1) && (myLab != prevLab);

    const size_t rowbase = (size_t)b << 8;        // b*T

    // t = 0: alpha0[s] = (s < 2) ? emit[0,s] : NEG
    float eb = lpb[rowbase];
    float el = lpl[(rowbase << 6) + lane];
    float a0 = (lane == 0) ? eb : NEGF;
    float a1 = (lane == 0) ? el : NEGF;
    float a2 = NEGF;

    for (int t = 1; t < 256; ++t) {
        eb = lpb[rowbase + t];
        el = lpl[((rowbase + t) << 6) + lane];
        float p1 = __shfl_up(a1, 1);              // alpha[2j-1]
        if (lane == 0) p1 = NEGF;
        float a1_63 = __shfl(a1, 63);             // alpha[127]
        float n0 = lse2(a0, p1) + eb;
        float n1 = lse3(a1, a0, skip ? p1 : NEGF) + el;
        float n2 = lse2(a2, a1_63) + eb;
        a0 = n0; a1 = n1; a2 = n2;
    }

    // tail = alpha[127], alpha[128]
    float t127 = __shfl(a1, 63);
    float ll = lse2(t127, a2);
    if (lane == 0)
        out[b] = -ll * 0.6931471805599453f;       // base-2 -> natural log
}

extern "C" void kernel_launch(void* const* d_in, const int* in_sizes, int n_in,
                              void* d_out, int out_size, void* d_ws, size_t ws_size,
                              hipStream_t stream) {
    const int*   y_true = (const int*)d_in[0];    // (B, L) int
    const float* y_pred = (const float*)d_in[1];  // (B, T, C) float32
    float* out = (float*)d_out;                   // (B, 1) float32

    float* lpl = (float*)d_ws;                            // B*T*64 floats
    float* lpb = lpl + (size_t)256 * 256 * 64;            // B*T floats
    // ws need: 16.78 MB + 0.26 MB = 17.04 MB

    emit_kernel<<<16384, 256, 0, stream>>>(y_pred, y_true, lpl, lpb);
    ctc_alpha_kernel<<<256, 64, 0, stream>>>(y_true, lpl, lpb, out);
}

// Round 2
// 421.878 us; speedup vs baseline: 1.0117x; 1.0117x over previous
//
#include <hip/hip_runtime.h>
#include <hip/hip_bf16.h>

// CTC forward loss, fused. B=256, T=256, C=1024, L=64, S=129, blank=1023.
//
// logp[b,t,c] = log(y+EPS) - log(rowsum + C*EPS)   (log_softmax over log(y+eps)
// collapses; no max-subtraction needed since exp(log(y+eps)) is exact).
// Only 65 classes/(b,t) are used: the 64 labels + blank. All logs in BASE 2
// (native v_exp_f32 / v_log_f32); final loglik scaled by ln2.
//
// One block per batch element: 16 waves compute the 256 row-sums + gathers
// into LDS (66.5 KB), then wave 0 runs the 255-step alpha recursion from LDS.
// Lane j holds alpha[2j] (blank, a0) and alpha[2j+1] (label j, a1);
// alpha[128] (a2) replicated. skip_ok only at odd pos 2j+1 iff j>=1 &&
// lab[j]!=lab[j-1].

#define NEGF (-1e30f)

__device__ __forceinline__ float lse2(float a, float b) {
    float m = fmaxf(a, b);
    return m + log2f(exp2f(a - m) + exp2f(b - m));
}
__device__ __forceinline__ float lse3(float a, float b, float c) {
    float m = fmaxf(fmaxf(a, b), c);
    return m + log2f(exp2f(a - m) + exp2f(b - m) + exp2f(c - m));
}

__global__ void __launch_bounds__(1024) ctc_fused_kernel(
    const float* __restrict__ y, const int* __restrict__ lab,
    float* __restrict__ out)
{
    __shared__ float lpl_s[256][64];   // [t][label-pos], 64 KB, conflict-free
    __shared__ float lpb_s[256];       // [t] blank logp, 1 KB

    const int b    = blockIdx.x;
    const int wave = threadIdx.x >> 6;
    const int lane = threadIdx.x & 63;

    const int myLab = lab[(b << 6) + lane];   // label j = lane (L=64)

    // ---- emit phase: wave w handles rows t = 16w .. 16w+15 ----
    for (int i = 0; i < 16; ++i) {
        const int t = (wave << 4) + i;
        const float* __restrict__ yr = y + ((size_t)(b * 256 + t) << 10);
        const float4* __restrict__ yr4 = (const float4*)yr;
        float4 v0 = yr4[lane];
        float4 v1 = yr4[lane + 64];
        float4 v2 = yr4[lane + 128];
        float4 v3 = yr4[lane + 192];
        float s = (v0.x + v0.y + v0.z + v0.w) + (v1.x + v1.y + v1.z + v1.w)
                + (v2.x + v2.y + v2.z + v2.w) + (v3.x + v3.y + v3.z + v3.w);
        #pragma unroll
        for (int off = 32; off; off >>= 1) s += __shfl_xor(s, off);
        const float norm = log2f(s + 1.024e-4f);      // log2(rowsum + C*EPS)
        const float yv = yr[myLab];                    // L1-hot gather
        lpl_s[t][lane] = log2f(yv + 1e-7f) - norm;
        if (lane == 0)
            lpb_s[t] = log2f(yr[1023] + 1e-7f) - norm; // blank = C-1
    }
    __syncthreads();

    if (wave != 0) return;   // 15 waves retire; wave 0 runs the recursion

    const int prevLab = __shfl_up(myLab, 1);
    const bool skip   = (lane >= 1) && (myLab != prevLab);

    // t = 0: alpha0[s] = (s < 2) ? emit[0,s] : NEG
    float eb = lpb_s[0];
    float el = lpl_s[0][lane];
    float a0 = (lane == 0) ? eb : NEGF;
    float a1 = (lane == 0) ? el : NEGF;
    float a2 = NEGF;

    for (int t = 1; t < 256; ++t) {
        eb = lpb_s[t];
        el = lpl_s[t][lane];
        float p1 = __shfl_up(a1, 1);              // alpha[2j-1]
        if (lane == 0) p1 = NEGF;
        float a1_63 = __shfl(a1, 63);             // alpha[127]
        float n0 = lse2(a0, p1) + eb;
        float n1 = lse3(a1, a0, skip ? p1 : NEGF) + el;
        float n2 = lse2(a2, a1_63) + eb;
        a0 = n0; a1 = n1; a2 = n2;
    }

    // tail = alpha[127], alpha[128]
    float t127 = __shfl(a1, 63);
    float ll = lse2(t127, a2);
    if (lane == 0)
        out[b] = -ll * 0.6931471805599453f;       // base-2 -> natural log
}

extern "C" void kernel_launch(void* const* d_in, const int* in_sizes, int n_in,
                              void* d_out, int out_size, void* d_ws, size_t ws_size,
                              hipStream_t stream) {
    const int*   y_true = (const int*)d_in[0];    // (B, L)
    const float* y_pred = (const float*)d_in[1];  // (B, T, C) float32
    float* out = (float*)d_out;                   // (B, 1) float32

    ctc_fused_kernel<<<256, 1024, 0, stream>>>(y_pred, y_true, out);
}

// Round 3
// 414.441 us; speedup vs baseline: 1.0299x; 1.0179x over previous
//
#include <hip/hip_runtime.h>
#include <hip/hip_bf16.h>

// CTC forward loss, fused. B=256, T=256, C=1024, L=64, S=129, blank=1023.
//
// logp[b,t,c] = log(y+EPS) - log(rowsum + C*EPS)   (log_softmax over log(y+eps)
// collapses). Only 65 classes/(b,t) are used: 64 labels + blank. Logs in BASE 2
// (native v_exp_f32/v_log_f32); final loglik scaled by ln2.
//
// One block (16 waves) per batch element. Emit phase: each wave handles 16
// rows in 4 chunks of 4 rows, with all 16 float4 loads of a chunk issued
// up-front (64 live VGPRs -> high MLP; round-2's VGPR=20 build serialized
// loads and hit only 805 GB/s). Then wave 0 runs the 255-step alpha
// recursion from LDS.

#define NEGF (-1e30f)

__device__ __forceinline__ float lse2(float a, float b) {
    float m = fmaxf(a, b);
    return m + log2f(exp2f(a - m) + exp2f(b - m));
}
__device__ __forceinline__ float lse3(float a, float b, float c) {
    float m = fmaxf(fmaxf(a, b), c);
    return m + log2f(exp2f(a - m) + exp2f(b - m) + exp2f(c - m));
}

__global__ void __launch_bounds__(1024, 4) ctc_fused_kernel(
    const float* __restrict__ y, const int* __restrict__ lab,
    float* __restrict__ out)
{
    __shared__ float lpl_s[256][64];   // [t][label-pos], 64 KB, conflict-free
    __shared__ float lpb_s[256];       // [t] blank logp, 1 KB

    const int b    = blockIdx.x;
    const int wave = threadIdx.x >> 6;
    const int lane = threadIdx.x & 63;

    const int myLab = lab[(b << 6) + lane];   // label j = lane (L=64)

    // ---- emit phase: wave w handles rows 16w..16w+15, 4 rows per chunk ----
    for (int chunk = 0; chunk < 4; ++chunk) {
        const int t0 = (wave << 4) + (chunk << 2);
        const float* __restrict__ yr0 = y + ((size_t)((b << 8) + t0) << 10);

        float4 v[4][4];
        #pragma unroll
        for (int r = 0; r < 4; ++r) {
            const float4* __restrict__ yr4 = (const float4*)(yr0 + ((size_t)r << 10));
            v[r][0] = yr4[lane];
            v[r][1] = yr4[lane + 64];
            v[r][2] = yr4[lane + 128];
            v[r][3] = yr4[lane + 192];
        }

        float s[4];
        #pragma unroll
        for (int r = 0; r < 4; ++r)
            s[r] = (v[r][0].x + v[r][0].y + v[r][0].z + v[r][0].w)
                 + (v[r][1].x + v[r][1].y + v[r][1].z + v[r][1].w)
                 + (v[r][2].x + v[r][2].y + v[r][2].z + v[r][2].w)
                 + (v[r][3].x + v[r][3].y + v[r][3].z + v[r][3].w);

        #pragma unroll
        for (int off = 32; off; off >>= 1) {
            #pragma unroll
            for (int r = 0; r < 4; ++r) s[r] += __shfl_xor(s[r], off);
        }

        // batched gathers (rows are L1/L2-hot from the streaming reads)
        float yv[4], nb[4];
        #pragma unroll
        for (int r = 0; r < 4; ++r) {
            const float* __restrict__ yr = yr0 + ((size_t)r << 10);
            yv[r] = yr[myLab];
            nb[r] = yr[1023];
        }
        #pragma unroll
        for (int r = 0; r < 4; ++r) {
            const float norm = log2f(s[r] + 1.024e-4f);   // log2(rowsum + C*EPS)
            lpl_s[t0 + r][lane] = log2f(yv[r] + 1e-7f) - norm;
            if (lane == 0)
                lpb_s[t0 + r] = log2f(nb[r] + 1e-7f) - norm;
        }
    }
    __syncthreads();

    if (wave != 0) return;   // 15 waves retire; wave 0 runs the recursion

    const int prevLab = __shfl_up(myLab, 1);
    const bool skip   = (lane >= 1) && (myLab != prevLab);

    // t = 0: alpha0[s] = (s < 2) ? emit[0,s] : NEG
    float eb = lpb_s[0];
    float el = lpl_s[0][lane];
    float a0 = (lane == 0) ? eb : NEGF;
    float a1 = (lane == 0) ? el : NEGF;
    float a2 = NEGF;

    // prefetch t=1
    float ebp = lpb_s[1];
    float elp = lpl_s[1][lane];

    for (int t = 1; t < 256; ++t) {
        eb = ebp; el = elp;
        if (t < 255) { ebp = lpb_s[t + 1]; elp = lpl_s[t + 1][lane]; }
        float p1 = __shfl_up(a1, 1);              // alpha[2j-1]
        if (lane == 0) p1 = NEGF;
        float a1_63 = __shfl(a1, 63);             // alpha[127]
        float n0 = lse2(a0, p1) + eb;
        float n1 = lse3(a1, a0, skip ? p1 : NEGF) + el;
        float n2 = lse2(a2, a1_63) + eb;
        a0 = n0; a1 = n1; a2 = n2;
    }

    // tail = alpha[127], alpha[128]
    float t127 = __shfl(a1, 63);
    float ll = lse2(t127, a2);
    if (lane == 0)
        out[b] = -ll * 0.6931471805599453f;       // base-2 -> natural log
}

extern "C" void kernel_launch(void* const* d_in, const int* in_sizes, int n_in,
                              void* d_out, int out_size, void* d_ws, size_t ws_size,
                              hipStream_t stream) {
    const int*   y_true = (const int*)d_in[0];    // (B, L)
    const float* y_pred = (const float*)d_in[1];  // (B, T, C) float32
    float* out = (float*)d_out;                   // (B, 1) float32

    ctc_fused_kernel<<<256, 1024, 0, stream>>>(y_pred, y_true, out);
}